// Round 9
// baseline (93.275 us; speedup 1.0000x reference)
//
#include <hip/hip_runtime.h>
#include <math.h>

#define B_   4
#define L_   4096
#define C_   512
#define DM_  1024
#define HID_ 128
#define M_   (B_*L_)    // 16384
#define NC_  512        // chunks of 8 rows
#define CT_  8

typedef __attribute__((ext_vector_type(8))) short short8;
typedef __attribute__((ext_vector_type(4))) float f32x4;

__device__ __forceinline__ unsigned short f2bf(float f) {
  unsigned u = __float_as_uint(f);
  u += 0x7fffu + ((u >> 16) & 1u);
  return (unsigned short)(u >> 16);
}
__device__ __forceinline__ float bf2f(unsigned v) {   // v = bf16 in low 16 bits
  return __uint_as_float(v << 16);
}

// wrap(-theta) into (-pi, pi] == atan2(sin(-t), cos(-t))
__device__ __forceinline__ float wrap_neg(float th) {
  return 6.283185307179586f * rintf(th * 0.15915494309189535f) - th;
}

// ---- prep: transpose+cast weights to bf16 [n][k]
__global__ __launch_bounds__(256) void k_prep(const float* __restrict__ W1,
                                              const float* __restrict__ W2,
                                              unsigned short* __restrict__ W1T,
                                              unsigned short* __restrict__ W2T) {
  int idx = blockIdx.x * 256 + threadIdx.x;
  if (idx < DM_ * HID_) {
    int n = idx >> 10, k = idx & 1023;
    W1T[idx] = f2bf(W1[(size_t)k * HID_ + n]);
  }
  int i2 = idx - DM_ * HID_;
  if (i2 >= 0 && i2 < HID_ * C_) {
    int n = i2 >> 7, k = i2 & 127;
    W2T[i2] = f2bf(W2[(size_t)k * C_ + n]);
  }
}

// ---- k_mlp: H=gelu(X@W1+b1) in LDS; logR=clip(H@W2+b2) -> u16 fixed-point ws.
__global__ __launch_bounds__(512) void k_mlp(const float* __restrict__ X,
                                             const unsigned short* __restrict__ W1T,
                                             const float* __restrict__ b1,
                                             const unsigned short* __restrict__ W2T,
                                             const float* __restrict__ b2,
                                             unsigned short* __restrict__ logRq) {
  __shared__ char lds[49152];
  const int tid  = threadIdx.x;
  const int m0   = blockIdx.x * 32;
  const int lane = tid & 63;
  const int wave = tid >> 6;
  const int wr   = wave >> 2;
  const int wc   = wave & 3;
  const int fr   = lane & 15;
  const int kg   = lane >> 4;

  f32x4 acc[2];
  acc[0] = (f32x4){0.f, 0.f, 0.f, 0.f};
  acc[1] = (f32x4){0.f, 0.f, 0.f, 0.f};

#define STAGE1(bufi, k0)                                                           \
  {                                                                                \
    if (tid < 256) {                                                               \
      int row = tid >> 3, k8 = tid & 7;                                            \
      const f32x4* src = (const f32x4*)(X + (size_t)(m0 + row) * DM_ + (k0) + k8 * 8); \
      f32x4 v0 = __builtin_nontemporal_load(src);                                  \
      f32x4 v1 = __builtin_nontemporal_load(src + 1);                              \
      uint4 pk;                                                                    \
      pk.x = f2bf(v0[0]) | ((unsigned)f2bf(v0[1]) << 16);                          \
      pk.y = f2bf(v0[2]) | ((unsigned)f2bf(v0[3]) << 16);                          \
      pk.z = f2bf(v1[0]) | ((unsigned)f2bf(v1[1]) << 16);                          \
      pk.w = f2bf(v1[2]) | ((unsigned)f2bf(v1[3]) << 16);                          \
      *(uint4*)(lds + (bufi) * 4096 + row * 128 + ((k8 ^ (row & 7)) << 4)) = pk;   \
    }                                                                              \
    _Pragma("unroll")                                                              \
    for (int t = 0; t < 2; ++t) {                                                  \
      int c = tid + t * 512;                                                       \
      int n = c >> 3, k8 = c & 7;                                                  \
      uint4 v = *(const uint4*)(W1T + (size_t)n * DM_ + (k0) + k8 * 8);            \
      *(uint4*)(lds + 8192 + (bufi) * 16384 + n * 128 + ((k8 ^ (n & 7)) << 4)) = v;\
    }                                                                              \
  }

  STAGE1(0, 0);
  __syncthreads();
  for (int it = 0; it < 16; ++it) {
    const int cur = it & 1;
    if (it < 15) STAGE1(1 - cur, (it + 1) * 64);
#pragma unroll
    for (int ks = 0; ks < 2; ++ks) {
      int row = wr * 16 + fr;
      short8 a = *(const short8*)(lds + cur * 4096 + row * 128 +
                                  (((ks * 4 + kg) ^ (row & 7)) << 4));
#pragma unroll
      for (int j = 0; j < 2; ++j) {
        int col = wc * 32 + j * 16 + fr;
        short8 b = *(const short8*)(lds + 8192 + cur * 16384 + col * 128 +
                                    (((ks * 4 + kg) ^ (col & 7)) << 4));
        acc[j] = __builtin_amdgcn_mfma_f32_16x16x32_bf16(a, b, acc[j], 0, 0, 0);
      }
    }
    __syncthreads();
  }
#pragma unroll
  for (int j = 0; j < 2; ++j) {
    int col = wc * 32 + j * 16 + fr;
    float bb = b1[col];
#pragma unroll
    for (int r = 0; r < 4; ++r) {
      int row = wr * 16 + kg * 4 + r;
      float x = acc[j][r] + bb;
      float g = 0.5f * x * (1.0f + erff(x * 0.70710678f));
      *(unsigned short*)(lds + 40960 + row * 256 +
                         (((col >> 3) ^ (row & 15)) << 4) + ((col & 7) << 1)) = f2bf(g);
    }
  }

#define STAGE2(bufi, nc)                                                           \
  {                                                                                \
    _Pragma("unroll")                                                              \
    for (int t = 0; t < 2; ++t) {                                                  \
      int c = tid + t * 512;                                                       \
      int n = c >> 4, k8 = c & 15;                                                 \
      uint4 v = *(const uint4*)(W2T + (size_t)((nc) * 64 + n) * HID_ + k8 * 8);    \
      *(uint4*)(lds + (bufi) * 16384 + n * 256 + ((k8 ^ (n & 15)) << 4)) = v;      \
    }                                                                              \
  }

  STAGE2(0, 0);
  __syncthreads();
  for (int nc = 0; nc < 8; ++nc) {
    const int cur = nc & 1;
    if (nc < 7) STAGE2(1 - cur, nc + 1);

    f32x4 a2 = (f32x4){0.f, 0.f, 0.f, 0.f};
#pragma unroll
    for (int ks = 0; ks < 4; ++ks) {
      int row = wr * 16 + fr;
      short8 af = *(const short8*)(lds + 40960 + row * 256 +
                                   (((ks * 4 + kg) ^ (row & 15)) << 4));
      int col = wc * 16 + fr;
      short8 bf2 = *(const short8*)(lds + cur * 16384 + col * 256 +
                                    (((ks * 4 + kg) ^ (col & 15)) << 4));
      a2 = __builtin_amdgcn_mfma_f32_16x16x32_bf16(af, bf2, a2, 0, 0, 0);
    }
    {
      int col = nc * 64 + wc * 16 + fr;
      float bb = b2[col];
#pragma unroll
      for (int r = 0; r < 4; ++r) {
        int row = m0 + wr * 16 + kg * 4 + r;
        float lr = a2[r] + bb;
        lr = fminf(5.0f, fmaxf(-5.0f, lr));
        logRq[(size_t)row * C_ + col] = (unsigned short)rintf((lr + 5.0f) * 6553.5f);
      }
    }
    __syncthreads();
  }
}

// ---- k_epi: pure stream, no barriers. 1024 blocks x 256 thr.
// thread = 4 channels x one 8-row chunk. Writes Pi/K/R (f32x4 NT), packed (A_t,s_t)
// bf16 pairs (ASq), and the chunk composite (Ab,Ub).
__global__ __launch_bounds__(256) void k_epi(const unsigned short* __restrict__ logRq,
                                             const float* __restrict__ logPi,
                                             const float* __restrict__ theta,
                                             float* __restrict__ out1,
                                             float* __restrict__ out2,
                                             float* __restrict__ out3,
                                             unsigned* __restrict__ ASq,
                                             float* __restrict__ Ab,
                                             float* __restrict__ Ub) {
  const int blk = blockIdx.x;
  const int b   = blk >> 8;
  const int cb  = blk & 255;           // 16-row tile
  const int g   = threadIdx.x & 127;
  const int h   = threadIdx.x >> 7;    // sub-chunk of 8 rows
  const int c0  = g * 4;
  const int row0 = cb * 16 + h * 8;
  const int ch   = cb * 2 + h;         // chunk index in [0,512)

  f32x4 lp = *(const f32x4*)(logPi + c0);
  f32x4 Pi4;
#pragma unroll
  for (int q = 0; q < 4; ++q) Pi4[q] = expf(lp[q]);

  f32x4 A4 = {1.f, 1.f, 1.f, 1.f}, U4 = {0.f, 0.f, 0.f, 0.f};
  const float dq = 1.0f / 6553.5f;
  const size_t base = ((size_t)b * L_ + row0) * C_ + c0;
#pragma unroll
  for (int j = 0; j < CT_; ++j) {
    size_t o = base + (size_t)j * C_;
    uint2 q2 = *(const uint2*)(logRq + o);
    f32x4 th = *(const f32x4*)(theta + o);
    float lr[4] = { (float)(q2.x & 0xffffu) * dq - 5.0f,
                    (float)(q2.x >> 16)     * dq - 5.0f,
                    (float)(q2.y & 0xffffu) * dq - 5.0f,
                    (float)(q2.y >> 16)     * dq - 5.0f };
    f32x4 R4, K4;
    uint4 pk;
#pragma unroll
    for (int q = 0; q < 4; ++q) {
      float R = expf(lr[q]);
      float K = Pi4[q] / fmaxf(Pi4[q] + R, 1e-8f);
      R4[q] = R; K4[q] = K;
      float nu = wrap_neg(th[q]);
      float a = 1.f - K;
      U4[q] = a * U4[q] + K * nu;
      A4[q] *= a;
      float s = th[q] + U4[q];
      (&pk.x)[q] = (unsigned)f2bf(A4[q]) | ((unsigned)f2bf(s) << 16);
    }
    __builtin_nontemporal_store(Pi4, (f32x4*)(out1 + o));
    __builtin_nontemporal_store(K4,  (f32x4*)(out2 + o));
    __builtin_nontemporal_store(R4,  (f32x4*)(out3 + o));
    *(uint4*)(ASq + o) = pk;          // re-read by scan3: keep cached
  }
  size_t co = ((size_t)(b * NC_ + ch)) * C_ + c0;
  *(f32x4*)(Ab + co) = A4;
  *(f32x4*)(Ub + co) = U4;
}

// ---- scan2: block-level prefix over 512 chunks for 16 channels
__global__ __launch_bounds__(256) void k_scan2(const float* __restrict__ Ab,
                                               const float* __restrict__ Ub,
                                               float* __restrict__ D0) {
  __shared__ float cA[16][17], cU[16][17], carry[16][17];
  const int tid = threadIdx.x;
  const int b   = blockIdx.x >> 5;
  const int c0  = (blockIdx.x & 31) * 16;
  const int c_l = tid & 15, s = tid >> 4;   // 16 segs x 32 chunks
  const int c   = c0 + c_l;
  float A = 1.f, U = 0.f;
#pragma unroll 4
  for (int k = 0; k < 32; ++k) {
    size_t o = ((size_t)(b * NC_ + s * 32 + k)) * C_ + c;
    float a = Ab[o], u = Ub[o];
    U = a * U + u; A *= a;
  }
  cA[s][c_l] = A; cU[s][c_l] = U;
  __syncthreads();
  if (tid < 16) {
    float P = 0.f;
#pragma unroll
    for (int ss = 0; ss < 16; ++ss) {
      carry[ss][tid] = P;
      P = cA[ss][tid] * P + cU[ss][tid];
    }
  }
  __syncthreads();
  float d = carry[s][c_l];
#pragma unroll 4
  for (int k = 0; k < 32; ++k) {
    size_t o = ((size_t)(b * NC_ + s * 32 + k)) * C_ + c;
    D0[o] = d;
    d = Ab[o] * d + Ub[o];
  }
}

// ---- scan3: pure elementwise, out0 = s_t + A_t * D0[chunk]. 16B/lane both ways.
__global__ __launch_bounds__(256) void k_scan3(const unsigned* __restrict__ ASq,
                                               const float* __restrict__ D0,
                                               float* __restrict__ out0) {
  size_t e = ((size_t)blockIdx.x * 256 + threadIdx.x) * 4;
  int row = (int)(e >> 9);
  int c0  = (int)(e & 511);
  int b   = row >> 12, l = row & 4095;
  int chk = l >> 3;
  uint4 q = *(const uint4*)(ASq + e);
  f32x4 d0 = *(const f32x4*)(D0 + (((size_t)(b * NC_ + chk)) << 9) + c0);
  f32x4 o;
#pragma unroll
  for (int i = 0; i < 4; ++i) {
    unsigned v = (&q.x)[i];
    o[i] = bf2f(v >> 16) + bf2f(v & 0xffffu) * d0[i];
  }
  __builtin_nontemporal_store(o, (f32x4*)(out0 + e));
}

extern "C" void kernel_launch(void* const* d_in, const int* in_sizes, int n_in,
                              void* d_out, int out_size, void* d_ws, size_t ws_size,
                              hipStream_t stream) {
  const float* theta = (const float*)d_in[0];
  const float* X     = (const float*)d_in[1];
  const float* logPi = (const float*)d_in[2];
  const float* W1    = (const float*)d_in[3];
  const float* b1    = (const float*)d_in[4];
  const float* W2    = (const float*)d_in[5];
  const float* b2    = (const float*)d_in[6];

  float* out = (float*)d_out;
  const size_t S = (size_t)M_ * C_;
  float* out0 = out;
  float* out1 = out + S;
  float* out2 = out + 2 * S;
  float* out3 = out + 3 * S;

  unsigned short* W1T   = (unsigned short*)d_ws;         // 131072 ush
  unsigned short* W2T   = W1T + (size_t)DM_ * HID_;      // 65536 ush
  unsigned short* logRq = W2T + (size_t)HID_ * C_;       // S ush (16 MiB)
  unsigned* ASq = (unsigned*)(logRq + S);                // S u32 (32 MiB)
  float* Ab = (float*)(ASq + S);                         // B*NC*C f32 (4 MiB)
  float* Ub = Ab + (size_t)B_ * NC_ * C_;
  float* D0 = Ub + (size_t)B_ * NC_ * C_;

  hipLaunchKernelGGL(k_prep, dim3(768), dim3(256), 0, stream, W1, W2, W1T, W2T);
  hipLaunchKernelGGL(k_mlp, dim3(M_ / 32), dim3(512), 0, stream,
                     X, W1T, b1, W2T, b2, logRq);
  hipLaunchKernelGGL(k_epi, dim3(B_ * 256), dim3(256), 0, stream,
                     logRq, logPi, theta, out1, out2, out3, ASq, Ab, Ub);
  hipLaunchKernelGGL(k_scan2, dim3(B_ * 32), dim3(256), 0, stream, Ab, Ub, D0);
  hipLaunchKernelGGL(k_scan3, dim3((int)(S / 1024)), dim3(256), 0, stream, ASq, D0, out0);
}

// Round 10
// 89.226 us; speedup vs baseline: 1.0454x; 1.0454x over previous
//
#include <hip/hip_runtime.h>
#include <math.h>

#define B_   4
#define L_   4096
#define C_   512
#define DM_  1024
#define HID_ 128
#define M_   (B_*L_)    // 16384
#define NC_  256        // chunks of 16 rows
#define CT_  16

typedef __attribute__((ext_vector_type(8))) short short8;
typedef __attribute__((ext_vector_type(4))) float f32x4;

__device__ __forceinline__ unsigned short f2bf(float f) {
  unsigned u = __float_as_uint(f);
  u += 0x7fffu + ((u >> 16) & 1u);
  return (unsigned short)(u >> 16);
}

// wrap(-theta) into (-pi, pi] == atan2(sin(-t), cos(-t))
__device__ __forceinline__ float wrap_neg(float th) {
  return 6.283185307179586f * rintf(th * 0.15915494309189535f) - th;
}

// ---- prep: transpose+cast weights to bf16 [n][k]
__global__ __launch_bounds__(256) void k_prep(const float* __restrict__ W1,
                                              const float* __restrict__ W2,
                                              unsigned short* __restrict__ W1T,
                                              unsigned short* __restrict__ W2T) {
  int idx = blockIdx.x * 256 + threadIdx.x;
  if (idx < DM_ * HID_) {
    int n = idx >> 10, k = idx & 1023;
    W1T[idx] = f2bf(W1[(size_t)k * HID_ + n]);
  }
  int i2 = idx - DM_ * HID_;
  if (i2 >= 0 && i2 < HID_ * C_) {
    int n = i2 >> 7, k = i2 & 127;
    W2T[i2] = f2bf(W2[(size_t)k * C_ + n]);
  }
}

// ---- k_mega: BM=32, 512 blocks, 512 thr. Phase1: A(X) LDS-staged (T14 split, dbuf,
//      1 barrier/iter), B(W1T) direct from L2 into regs. One barrier at H. Phase2:
//      zero barriers — H from LDS, B(W2T) direct L2, prefetched; epilogue writes
//      Pi/K/R + in-register 16-row affine composites (kg-butterfly).
// LDS: A dbuf [0,8192) (2 x 32x64 bf16 swizzled), H [8192,16896) 32x(136sh=272B)
__global__ __launch_bounds__(512) void k_mega(const float* __restrict__ X,
                                              const unsigned short* __restrict__ W1T,
                                              const float* __restrict__ b1,
                                              const unsigned short* __restrict__ W2T,
                                              const float* __restrict__ b2,
                                              const float* __restrict__ logPi,
                                              const float* __restrict__ theta,
                                              float* __restrict__ out1,
                                              float* __restrict__ out2,
                                              float* __restrict__ out3,
                                              float* __restrict__ Ab,
                                              float* __restrict__ Ub) {
  __shared__ char lds[16896];
  const int tid  = threadIdx.x;
  const int m0   = blockIdx.x * 32;
  const int lane = tid & 63;
  const int wave = tid >> 6;
  const int wr   = wave >> 2;      // 0..1 : 16-row half
  const int wc   = wave & 3;       // 0..3 : col group
  const int fr   = lane & 15;
  const int kg   = lane >> 4;      // 0..3

  // ---------------- phase 1: H = gelu(X @ W1 + b1), 32x128 ----------------
  // staging ids: all 512 threads, 4 f32 each per iter
  const int srow = tid >> 4;       // 0..31
  const int sk4  = tid & 15;       // 0..15
  const float* xsrc = X + (size_t)(m0 + srow) * DM_ + sk4 * 4;
  char* swr = lds + srow * 128 + ((sk4 << 3) ^ ((srow & 7) << 4));

  const unsigned short* w1p0 = W1T + (size_t)(wc * 32 + fr) * DM_ + kg * 8;
  const unsigned short* w1p1 = W1T + (size_t)(wc * 32 + 16 + fr) * DM_ + kg * 8;

  f32x4 acc0 = {0.f, 0.f, 0.f, 0.f};
  f32x4 acc1 = {0.f, 0.f, 0.f, 0.f};

  {  // prologue: stage iter 0
    f32x4 xv = __builtin_nontemporal_load((const f32x4*)xsrc);
    unsigned p0 = f2bf(xv[0]) | ((unsigned)f2bf(xv[1]) << 16);
    unsigned p1 = f2bf(xv[2]) | ((unsigned)f2bf(xv[3]) << 16);
    uint2 pk = {p0, p1};
    *(uint2*)swr = pk;
  }
  __syncthreads();

  short8 bc[4], bn[4];     // bc[ks*2+j]
  bc[0] = *(const short8*)(w1p0);
  bc[1] = *(const short8*)(w1p1);
  bc[2] = *(const short8*)(w1p0 + 32);
  bc[3] = *(const short8*)(w1p1 + 32);

  const int arow = wr * 16 + fr;
  char* ard = lds + arow * 128;

  for (int it = 0; it < 16; ++it) {
    const int cur = it & 1;
    f32x4 xv;
    if (it < 15) {                       // T14: issue loads early
      xv = __builtin_nontemporal_load((const f32x4*)(xsrc + (it + 1) * 64));
      const unsigned short* p0 = w1p0 + (it + 1) * 64;
      const unsigned short* p1 = w1p1 + (it + 1) * 64;
      bn[0] = *(const short8*)(p0);
      bn[1] = *(const short8*)(p1);
      bn[2] = *(const short8*)(p0 + 32);
      bn[3] = *(const short8*)(p1 + 32);
    }
#pragma unroll
    for (int ks = 0; ks < 2; ++ks) {
      short8 a = *(const short8*)(ard + cur * 4096 +
                                  (((ks * 4 + kg) << 4) ^ ((arow & 7) << 4)));
      acc0 = __builtin_amdgcn_mfma_f32_16x16x32_bf16(a, bc[ks * 2 + 0], acc0, 0, 0, 0);
      acc1 = __builtin_amdgcn_mfma_f32_16x16x32_bf16(a, bc[ks * 2 + 1], acc1, 0, 0, 0);
    }
    if (it < 15) {                       // T14: LDS write late
      unsigned p0 = f2bf(xv[0]) | ((unsigned)f2bf(xv[1]) << 16);
      unsigned p1 = f2bf(xv[2]) | ((unsigned)f2bf(xv[3]) << 16);
      uint2 pk = {p0, p1};
      *(uint2*)(swr + (1 - cur) * 4096) = pk;
      __syncthreads();
#pragma unroll
      for (int q = 0; q < 4; ++q) bc[q] = bn[q];
    }
  }

  // H epilogue -> LDS [8192,16896), row stride 272 B
#pragma unroll
  for (int j = 0; j < 2; ++j) {
    int col = wc * 32 + j * 16 + fr;
    float bb = b1[col];
    f32x4 av = (j == 0) ? acc0 : acc1;
#pragma unroll
    for (int r = 0; r < 4; ++r) {
      int row = wr * 16 + kg * 4 + r;
      float x = av[r] + bb;
      float g = 0.5f * x * (1.0f + erff(x * 0.70710678f));
      *(unsigned short*)(lds + 8192 + row * 272 + col * 2) = f2bf(g);
    }
  }
  __syncthreads();

  // ---------------- phase 2: zero barriers ----------------
  const int bidx = blockIdx.x >> 7;                  // batch
  const int ch   = ((m0 & 4095) >> 4) + wr;          // 16-row chunk
  const size_t chbase = ((size_t)(bidx * NC_ + ch)) * C_;
  const int colbase = wc * 16 + fr;
  const unsigned short* w2p = W2T + (size_t)colbase * HID_ + kg * 8;
  const char* hrd = lds + 8192 + (wr * 16 + fr) * 272;
  const size_t throw0 = (size_t)(m0 + wr * 16 + kg * 4) * C_;

  short8 c2[4], n2[4];
#pragma unroll
  for (int ks = 0; ks < 4; ++ks) c2[ks] = *(const short8*)(w2p + ks * 32);
  float thc[4], thn[4];
#pragma unroll
  for (int r = 0; r < 4; ++r) thc[r] = theta[throw0 + (size_t)r * C_ + colbase];

  for (int nc = 0; nc < 8; ++nc) {
    const int col = nc * 64 + colbase;
    if (nc < 7) {                        // prefetch next B-frags + theta
#pragma unroll
      for (int ks = 0; ks < 4; ++ks)
        n2[ks] = *(const short8*)(w2p + (size_t)(nc + 1) * 64 * HID_ + ks * 32);
#pragma unroll
      for (int r = 0; r < 4; ++r)
        thn[r] = theta[throw0 + (size_t)r * C_ + col + 64];
    }
    float Pi = expf(logPi[col]);
    float bb = b2[col];

    f32x4 a2 = {0.f, 0.f, 0.f, 0.f};
#pragma unroll
    for (int ks = 0; ks < 4; ++ks) {
      short8 a = *(const short8*)(hrd + ks * 64 + kg * 16);
      a2 = __builtin_amdgcn_mfma_f32_16x16x32_bf16(a, c2[ks], a2, 0, 0, 0);
    }

    // epilogue + in-register 16-row chunk composition
    float A = 1.f, U = 0.f;
#pragma unroll
    for (int r = 0; r < 4; ++r) {
      int row = m0 + wr * 16 + kg * 4 + r;
      float lr = a2[r] + bb;
      lr = fminf(5.0f, fmaxf(-5.0f, lr));
      float R = expf(lr);
      float K = Pi / fmaxf(Pi + R, 1e-8f);
      size_t o = (size_t)row * C_ + col;
      __builtin_nontemporal_store(Pi, &out1[o]);
      out2[o] = K;                       // re-read by scan3
      __builtin_nontemporal_store(R, &out3[o]);
      float nu = wrap_neg(thc[r]);
      float a = 1.f - K;
      U = a * U + K * nu;
      A = a * A;
    }
    // ordered combine across kg lanes (butterfly)
    float oA = __shfl_xor(A, 16), oU = __shfl_xor(U, 16);
    if ((kg & 1) == 0) { U = oA * U + oU; A = oA * A; }
    else               { U = A * oU + U;  A = A * oA; }
    oA = __shfl_xor(A, 32); oU = __shfl_xor(U, 32);
    if ((kg & 2) == 0) { U = oA * U + oU; A = oA * A; }
    else               { U = A * oU + U;  A = A * oA; }
    if (kg == 0) { Ab[chbase + col] = A; Ub[chbase + col] = U; }

    if (nc < 7) {
#pragma unroll
      for (int ks = 0; ks < 4; ++ks) c2[ks] = n2[ks];
#pragma unroll
      for (int r = 0; r < 4; ++r) thc[r] = thn[r];
    }
  }
}

// ---- scan2: block-level prefix over 256 chunks for 16 channels
__global__ __launch_bounds__(256) void k_scan2(const float* __restrict__ Ab,
                                               const float* __restrict__ Ub,
                                               float* __restrict__ D0) {
  __shared__ float cA[16][17], cU[16][17], carry[16][17];
  const int tid = threadIdx.x;
  const int b   = blockIdx.x >> 5;
  const int c0  = (blockIdx.x & 31) * 16;
  const int c_l = tid & 15, s = tid >> 4;   // 16 segs x 16 chunks
  const int c   = c0 + c_l;
  float A = 1.f, U = 0.f;
#pragma unroll
  for (int k = 0; k < 16; ++k) {
    size_t o = ((size_t)(b * NC_ + s * 16 + k)) * C_ + c;
    float a = Ab[o], u = Ub[o];
    U = a * U + u; A *= a;
  }
  cA[s][c_l] = A; cU[s][c_l] = U;
  __syncthreads();
  if (tid < 16) {
    float P = 0.f;
#pragma unroll
    for (int ss = 0; ss < 16; ++ss) {
      carry[ss][tid] = P;
      P = cA[ss][tid] * P + cU[ss][tid];
    }
  }
  __syncthreads();
  float d = carry[s][c_l];
#pragma unroll
  for (int k = 0; k < 16; ++k) {
    size_t o = ((size_t)(b * NC_ + s * 16 + k)) * C_ + c;
    D0[o] = d;
    d = Ab[o] * d + Ub[o];
  }
}

// ---- scan3: apply carry, out0 = theta + d
__global__ __launch_bounds__(256) void k_scan3(const float* __restrict__ Kv,
                                               const float* __restrict__ theta,
                                               const float* __restrict__ D0,
                                               float* __restrict__ out0) {
  const int b  = blockIdx.x / NC_;
  const int ch = blockIdx.x % NC_;
  const int c  = blockIdx.y * 256 + threadIdx.x;
  size_t base = ((size_t)b * L_ + (size_t)ch * CT_) * C_ + c;
  float d = D0[((size_t)(b * NC_ + ch)) * C_ + c];
#pragma unroll 4
  for (int j = 0; j < CT_; ++j) {
    size_t idx = base + (size_t)j * C_;
    float k  = Kv[idx];
    float th = theta[idx];
    float nu = wrap_neg(th);
    d = (1.f - k) * d + k * nu;
    __builtin_nontemporal_store(th + d, &out0[idx]);
  }
}

extern "C" void kernel_launch(void* const* d_in, const int* in_sizes, int n_in,
                              void* d_out, int out_size, void* d_ws, size_t ws_size,
                              hipStream_t stream) {
  const float* theta = (const float*)d_in[0];
  const float* X     = (const float*)d_in[1];
  const float* logPi = (const float*)d_in[2];
  const float* W1    = (const float*)d_in[3];
  const float* b1    = (const float*)d_in[4];
  const float* W2    = (const float*)d_in[5];
  const float* b2    = (const float*)d_in[6];

  float* out = (float*)d_out;
  const size_t S = (size_t)M_ * C_;
  float* out0 = out;
  float* out1 = out + S;
  float* out2 = out + 2 * S;
  float* out3 = out + 3 * S;

  unsigned short* W1T = (unsigned short*)d_ws;           // 131072 ush
  unsigned short* W2T = W1T + (size_t)DM_ * HID_;        // 65536 ush
  float* Ab = (float*)(W2T + (size_t)HID_ * C_);         // B*NC*C f32 each (2 MiB)
  float* Ub = Ab + (size_t)B_ * NC_ * C_;
  float* D0 = Ub + (size_t)B_ * NC_ * C_;

  hipLaunchKernelGGL(k_prep, dim3(768), dim3(256), 0, stream, W1, W2, W1T, W2T);
  hipLaunchKernelGGL(k_mega, dim3(M_ / 32), dim3(512), 0, stream,
                     X, W1T, b1, W2T, b2, logPi, theta, out1, out2, out3, Ab, Ub);
  hipLaunchKernelGGL(k_scan2, dim3(B_ * 32), dim3(256), 0, stream, Ab, Ub, D0);
  hipLaunchKernelGGL(k_scan3, dim3(B_ * NC_, 2), dim3(256), 0, stream, out2, theta, D0, out0);
}